// Round 14
// baseline (24941.110 us; speedup 1.0000x reference)
//
#include <hip/hip_runtime.h>

#define DEV __device__ __forceinline__

namespace {
constexpr int Bc = 32;
constexpr int Tc = 256;
constexpr int Dc = 512;
constexpr int NBLK = 256;
constexpr int NW   = 128;          // writer blocks (own 16 mem rows each)
constexpr int ROWS = 16;
constexpr int NT   = 512;          // threads per k_main block (8 waves)

// rp: [2][NW][B][Dc/4] u64 packets, each = 4 bf16 cols
constexpr size_t RP16PAR = (size_t)NW * Bc * (Dc / 4);   // u64 per parity

// workspace layout (float offsets)
constexpr size_t OFF_KN   = 0;                                  // [T][B][D] normalized k
constexpr size_t OFF_E    = OFF_KN + (size_t)Tc * Bc * Dc;      // [T][B][D] sigmoid(erase)
constexpr size_t OFF_A    = OFF_E  + (size_t)Tc * Bc * Dc;      // [T][B][D] add
constexpr size_t OFF_RP   = OFF_A  + (size_t)Tc * Bc * Dc;      // 2*RP16PAR u64
constexpr size_t OFF_DEN  = OFF_RP + 2 * RP16PAR * 2;           // [T][B] den accumulators
constexpr size_t OFF_FLAGS= OFF_DEN + (size_t)Tc * Bc;          // 256*16 u32 arrival flags
}

DEV float sigm(float x) { return 1.0f / (1.0f + __expf(-x)); }

// Agent-scope relaxed helpers (proven coherent across XCDs, R3-R13).
DEV float ld1cg(const float* p) {
  unsigned u = __hip_atomic_load((const unsigned*)p, __ATOMIC_RELAXED,
                                 __HIP_MEMORY_SCOPE_AGENT);
  return __uint_as_float(u);
}
DEV unsigned long long ld8cg(const unsigned long long* p) {
  return __hip_atomic_load(p, __ATOMIC_RELAXED, __HIP_MEMORY_SCOPE_AGENT);
}
DEV void st8cg(unsigned long long* p, unsigned long long v) {
  __hip_atomic_store(p, v, __ATOMIC_RELAXED, __HIP_MEMORY_SCOPE_AGENT);
}

DEV unsigned pack_bf2(float x, float y) {   // RNE f32->bf16 pair (R8-proven)
  unsigned ux = __float_as_uint(x), uy = __float_as_uint(y);
  unsigned rx = (ux + 0x7FFFu + ((ux >> 16) & 1u)) >> 16;
  unsigned ry = (uy + 0x7FFFu + ((uy >> 16) & 1u)) >> 16;
  return rx | (ry << 16);
}
DEV float lo16f(unsigned u) { return __uint_as_float(u << 16); }
DEV float hi16f(unsigned u) { return __uint_as_float(u & 0xFFFF0000u); }

// LDS-only block barrier: does NOT drain vmcnt, so deferred global stores
// keep floating across it (rule #18: sched_barrier fences around).
DEV void lbar() {
  asm volatile("s_waitcnt lgkmcnt(0)" ::: "memory");
  __builtin_amdgcn_sched_barrier(0);
  __builtin_amdgcn_s_barrier();
  __builtin_amdgcn_sched_barrier(0);
}

// ---------------------------------------------------------------------------
// K1: 4 fused controller GEMMs (unchanged, validated).
// ---------------------------------------------------------------------------
__global__ __launch_bounds__(256) void k_gemm(
    const float* __restrict__ A,
    const float* __restrict__ Wk, const float* __restrict__ bk,
    const float* __restrict__ We, const float* __restrict__ be,
    const float* __restrict__ Ww, const float* __restrict__ bw,
    const float* __restrict__ Wg, const float* __restrict__ bg,
    float* __restrict__ ws, float* __restrict__ gout)
{
  __shared__ float As[32][68];
  __shared__ float Bs[32][68];

  const int bid = blockIdx.x;
  const int mat = bid >> 10;
  const int rem = bid & 1023;
  const int rt = rem >> 3, jt = rem & 7;
  const int rbase = rt * 64, jbase = jt * 64;

  const float* Wm; const float* bm;
  if      (mat == 0) { Wm = Wk; bm = bk; }
  else if (mat == 1) { Wm = We; bm = be; }
  else if (mat == 2) { Wm = Ww; bm = bw; }
  else               { Wm = Wg; bm = bg; }

  const int tid = threadIdx.x;
  const int lr = tid >> 2;
  const int lk = (tid & 3) * 8;
  const int ty = tid >> 4, tx = tid & 15;

  float acc[4][4] = {};

  for (int k0 = 0; k0 < Dc; k0 += 32) {
    const float4 a0 = *(const float4*)&A [(size_t)(rbase + lr) * Dc + k0 + lk];
    const float4 a1 = *(const float4*)&A [(size_t)(rbase + lr) * Dc + k0 + lk + 4];
    const float4 b0 = *(const float4*)&Wm[(size_t)(jbase + lr) * Dc + k0 + lk];
    const float4 b1 = *(const float4*)&Wm[(size_t)(jbase + lr) * Dc + k0 + lk + 4];
    __syncthreads();
    As[lk + 0][lr] = a0.x; As[lk + 1][lr] = a0.y; As[lk + 2][lr] = a0.z; As[lk + 3][lr] = a0.w;
    As[lk + 4][lr] = a1.x; As[lk + 5][lr] = a1.y; As[lk + 6][lr] = a1.z; As[lk + 7][lr] = a1.w;
    Bs[lk + 0][lr] = b0.x; Bs[lk + 1][lr] = b0.y; Bs[lk + 2][lr] = b0.z; Bs[lk + 3][lr] = b0.w;
    Bs[lk + 4][lr] = b1.x; Bs[lk + 5][lr] = b1.y; Bs[lk + 6][lr] = b1.z; Bs[lk + 7][lr] = b1.w;
    __syncthreads();
    #pragma unroll
    for (int kk = 0; kk < 32; ++kk) {
      const float4 av = *(const float4*)&As[kk][ty * 4];
      const float4 bv = *(const float4*)&Bs[kk][tx * 4];
      const float ar[4] = {av.x, av.y, av.z, av.w};
      const float br[4] = {bv.x, bv.y, bv.z, bv.w};
      #pragma unroll
      for (int i = 0; i < 4; ++i)
        #pragma unroll
        for (int j = 0; j < 4; ++j)
          acc[i][j] = fmaf(ar[i], br[j], acc[i][j]);
    }
  }

  const float4 bias = *(const float4*)&bm[jbase + tx * 4];
  const float bi[4] = {bias.x, bias.y, bias.z, bias.w};
  #pragma unroll
  for (int i = 0; i < 4; ++i) {
    const int r = rbase + ty * 4 + i;
    float v[4];
    #pragma unroll
    for (int j = 0; j < 4; ++j) {
      v[j] = acc[i][j] + bi[j];
      if (mat & 1) v[j] = sigm(v[j]);
    }
    float4 o; o.x = v[0]; o.y = v[1]; o.z = v[2]; o.w = v[3];
    if (mat == 3) {
      *(float4*)&gout[(size_t)r * Dc + jbase + tx * 4] = o;   // g -> d_out (temp)
    } else {
      float* dst = ws + (mat == 0 ? OFF_KN : (mat == 1 ? OFF_E : OFF_A));
      const int t = r & 255, b = r >> 8;                      // r = b*T + t
      *(float4*)&dst[((size_t)t * Bc + b) * Dc + jbase + tx * 4] = o;
    }
  }
}

// ---------------------------------------------------------------------------
// K2: l2-normalize k rows in place (unchanged).
// ---------------------------------------------------------------------------
__global__ __launch_bounds__(256) void k_knorm(float* __restrict__ kn)
{
  const int row = blockIdx.x * 4 + (threadIdx.x >> 6);
  const int lane = threadIdx.x & 63;
  float* p = kn + (size_t)row * Dc;
  float4 v0 = *(const float4*)&p[lane * 4];
  float4 v1 = *(const float4*)&p[256 + lane * 4];
  float ss = v0.x*v0.x + v0.y*v0.y + v0.z*v0.z + v0.w*v0.w
           + v1.x*v1.x + v1.y*v1.y + v1.z*v1.z + v1.w*v1.w;
  #pragma unroll
  for (int off = 32; off >= 1; off >>= 1) ss += __shfl_xor(ss, off);
  const float inv = 1.0f / fmaxf(sqrtf(ss), 1e-12f);
  v0.x *= inv; v0.y *= inv; v0.z *= inv; v0.w *= inv;
  v1.x *= inv; v1.y *= inv; v1.z *= inv; v1.w *= inv;
  *(float4*)&p[lane * 4] = v0;
  *(float4*)&p[256 + lane * 4] = v1;
}

// ---------------------------------------------------------------------------
// Single-hop all-to-all barrier; threads 0..255 poll one flag each (proven).
// The __syncthreads drains vmcnt(0): releases this step's deferred stores.
// ---------------------------------------------------------------------------
DEV void gbar(unsigned* flags, unsigned step, int bid, int tid)
{
  __syncthreads();
  if (tid == 0)
    __hip_atomic_store(&flags[bid * 16], step, __ATOMIC_RELAXED,
                       __HIP_MEMORY_SCOPE_AGENT);
  if (tid < 256) {
    while (__hip_atomic_load(&flags[tid * 16], __ATOMIC_RELAXED,
                             __HIP_MEMORY_SCOPE_AGENT) < step)
      __builtin_amdgcn_s_sleep(1);
  }
  __syncthreads();
}

// ---------------------------------------------------------------------------
// sim phase (512t): thread = (row r = tid>>5, batch bp = tid&31).
// LDS-only barrier inside; ends with 32 device-scope atomicAdds into den.
// ---------------------------------------------------------------------------
DEV void sim_phase(const float* __restrict__ knp, float* __restrict__ den_next,
                   const float (*y)[516], float* __restrict__ ew_own,
                   const float* invn_s, int tid)
{
  const int r = tid >> 5, bp = tid & 31;
  const float* kp = knp + (size_t)bp * Dc;
  float acc = 0.f;
  #pragma unroll 4
  for (int dq = 0; dq < Dc / 4; ++dq) {
    const float4 y4 = *(const float4*)&y[r][dq * 4];
    const float4 k4 = *(const float4*)&kp[dq * 4];
    acc = fmaf(y4.x, k4.x, acc); acc = fmaf(y4.y, k4.y, acc);
    acc = fmaf(y4.z, k4.z, acc); acc = fmaf(y4.w, k4.w, acc);
  }
  ew_own[tid] = __expf(acc * invn_s[r]);   // layout [r][bp] == tid
  lbar();
  if (tid < 32) {
    float s = 0.f;
    #pragma unroll
    for (int r2 = 0; r2 < 16; ++r2) s += ew_own[r2 * 32 + tid];
    atomicAdd(&den_next[tid], s);          // device-scope accumulate
  }
}

// ---------------------------------------------------------------------------
// Persistent recurrent kernel: 256 blocks x 512 threads (8 waves/CU).
// rp pipeline is 3-deep: compute rpv[t] in step t (held in VGPRs), store it
// (bf16x4 u64) at the START of step t+1 (drains under that step's compute),
// reducers consume at t+2. Intra-step W barriers are LDS-only (lbar).
// ---------------------------------------------------------------------------
__global__ __launch_bounds__(NT) void k_main(
    const float* __restrict__ cs, const float* __restrict__ mem_in,
    const float* __restrict__ gamma, const float* __restrict__ beta,
    float* __restrict__ ws, float* __restrict__ out)
{
  __shared__ float mrows[16][516];   // persistent memory rows (W)
  __shared__ float ew_own[512];      // [r][bp] exp(sim) at current t (W)
  __shared__ float wbuf[16][32];
  __shared__ float redR[16][128];    // reducer partial-group sums
  __shared__ float mu_s[16], rs_s[16], invn_s[16], dinv_s[32];

  float* kn   = ws + OFF_KN;
  float* eptb = ws + OFF_E;
  float* aptb = ws + OFF_A;
  unsigned long long* rp16 = (unsigned long long*)(ws + OFF_RP);
  float* den  = ws + OFF_DEN;
  unsigned* flags = (unsigned*)(ws + OFF_FLAGS);

  const int bid = blockIdx.x, tid = threadIdx.x;
  const float inv32 = 1.0f / 32.0f;

  float ev[32], av[32];              // e[t]/a[t] resident (W)
  float rpv[32];                     // rp[t] held across the step boundary (W)
  const float gmv = gamma[tid & 511];
  const float btv = beta[tid & 511];

  if (bid < NW) {
    const int s0 = bid * ROWS;
    #pragma unroll
    for (int r = 0; r < ROWS; ++r)
      mrows[r][tid] = mem_in[(size_t)(s0 + r) * Dc + tid];
    #pragma unroll
    for (int b = 0; b < 32; ++b) {
      ev[b] = eptb[(size_t)b * Dc + tid];
      av[b] = aptb[(size_t)b * Dc + tid];
    }
    __syncthreads();
    {
      const int row = tid >> 5, li = tid & 31;
      float ss = 0.f;
      #pragma unroll
      for (int i = 0; i < 4; ++i) {
        const float4 v = *(const float4*)&mrows[row][(li + i * 32) * 4];
        ss += v.x*v.x + v.y*v.y + v.z*v.z + v.w*v.w;
      }
      ss += __shfl_xor(ss, 16); ss += __shfl_xor(ss, 8);
      ss += __shfl_xor(ss, 4);  ss += __shfl_xor(ss, 2);
      ss += __shfl_xor(ss, 1);
      if (li == 0) invn_s[row] = 1.0f / fmaxf(sqrtf(ss), 1e-12f);
    }
    __syncthreads();
    sim_phase(kn, den, mrows, ew_own, invn_s, tid);   // accumulates den[0]
  }
  gbar(flags, 1u, bid, tid);

  for (int t = 0; t <= Tc + 1; ++t) {
    if (bid < NW) {
      // 0) early den[t] load (oldest in vmcnt queue, ahead of the stores)
      float dvv = 0.f;
      if (t < Tc - 1 && tid < 32) dvv = ld1cg(&den[(size_t)t * Bc + tid]);

      // 1) deferred store of rp[t-1] (bf16x4 u64); drains under this step
      if (t >= 1 && t <= Tc) {
        unsigned long long* dst = rp16 + (size_t)((t - 1) & 1) * RP16PAR
                                + (size_t)bid * Bc * (Dc / 4);
        const int cu = tid >> 2;
        #pragma unroll
        for (int b = 0; b < 32; ++b) {
          const float o1 = __shfl_xor(rpv[b], 1);
          const unsigned w = pack_bf2(rpv[b], o1);
          const unsigned w2 = (unsigned)__shfl_xor((int)w, 2);
          if ((tid & 3) == 0)
            st8cg(&dst[(size_t)b * (Dc / 4) + cu],
                  (unsigned long long)w | ((unsigned long long)w2 << 32));
        }
      }

      if (t < Tc) {
        // 2) compute rp[t] (unnormalized) from ew_own & current mrows
        float mr[16];
        #pragma unroll
        for (int r = 0; r < ROWS; ++r) mr[r] = mrows[r][tid];
        #pragma unroll
        for (int b = 0; b < 32; ++b) rpv[b] = 0.f;
        #pragma unroll
        for (int r = 0; r < ROWS; ++r) {
          const float mrr = mr[r];
          #pragma unroll
          for (int b4 = 0; b4 < 8; ++b4) {
            const float4 e4 = *(const float4*)&ew_own[r * 32 + b4 * 4];
            rpv[b4*4+0] = fmaf(e4.x, mrr, rpv[b4*4+0]);
            rpv[b4*4+1] = fmaf(e4.y, mrr, rpv[b4*4+1]);
            rpv[b4*4+2] = fmaf(e4.z, mrr, rpv[b4*4+2]);
            rpv[b4*4+3] = fmaf(e4.w, mrr, rpv[b4*4+3]);
          }
        }

        if (t < Tc - 1) {
          // 3) normalized weights
          if (tid < 32) dinv_s[tid] = 1.0f / dvv;
          lbar();
          wbuf[tid >> 5][tid & 31] = ew_own[tid] * dinv_s[tid & 31];
          lbar();

          // 4) erase/add pass
          float er[16] = {}, ad[16] = {};
          #pragma unroll
          for (int r = 0; r < ROWS; ++r) {
            #pragma unroll
            for (int b4 = 0; b4 < 8; ++b4) {
              const float4 w4 = *(const float4*)&wbuf[r][b4 * 4];
              er[r] = fmaf(w4.x, ev[b4*4+0], er[r]);
              er[r] = fmaf(w4.y, ev[b4*4+1], er[r]);
              er[r] = fmaf(w4.z, ev[b4*4+2], er[r]);
              er[r] = fmaf(w4.w, ev[b4*4+3], er[r]);
              ad[r] = fmaf(w4.x, av[b4*4+0], ad[r]);
              ad[r] = fmaf(w4.y, av[b4*4+1], ad[r]);
              ad[r] = fmaf(w4.z, av[b4*4+2], ad[r]);
              ad[r] = fmaf(w4.w, av[b4*4+3], ad[r]);
            }
          }
          // 5) x = m*(1-er/32) + ad/32, staged to mrows
          float xr[16];
          #pragma unroll
          for (int r = 0; r < ROWS; ++r) {
            const float x = mr[r] * (1.0f - er[r] * inv32) + ad[r] * inv32;
            xr[r] = x;
            mrows[r][tid] = x;
          }
          // 6) prefetch e/a for t+1
          if (t <= Tc - 3) {
            const float* ep1 = eptb + (size_t)(t + 1) * Bc * Dc;
            const float* ap1 = aptb + (size_t)(t + 1) * Bc * Dc;
            #pragma unroll
            for (int b = 0; b < 32; ++b) {
              ev[b] = ep1[(size_t)b * Dc + tid];
              av[b] = ap1[(size_t)b * Dc + tid];
            }
          }
          lbar();
          // 7) LN stats
          {
            const int row = tid >> 5, li = tid & 31;
            float s1 = 0.f, s2 = 0.f;
            #pragma unroll
            for (int i = 0; i < 4; ++i) {
              const float4 v = *(const float4*)&mrows[row][(li + i * 32) * 4];
              s1 += v.x + v.y + v.z + v.w;
              s2 += v.x*v.x + v.y*v.y + v.z*v.z + v.w*v.w;
            }
            s1 += __shfl_xor(s1, 16); s2 += __shfl_xor(s2, 16);
            s1 += __shfl_xor(s1, 8);  s2 += __shfl_xor(s2, 8);
            s1 += __shfl_xor(s1, 4);  s2 += __shfl_xor(s2, 4);
            s1 += __shfl_xor(s1, 2);  s2 += __shfl_xor(s2, 2);
            s1 += __shfl_xor(s1, 1);  s2 += __shfl_xor(s2, 1);
            if (li == 0) {
              const float mu = s1 * (1.0f / 512.0f);
              const float var = s2 * (1.0f / 512.0f) - mu * mu;
              mu_s[row] = mu;
              rs_s[row] = rsqrtf(var + 1e-5f);
            }
          }
          lbar();
          // 8) apply LN into mrows
          #pragma unroll
          for (int r = 0; r < ROWS; ++r) {
            const float y = (xr[r] - mu_s[r]) * rs_s[r] * gmv + btv;
            mrows[r][tid] = y;
          }
          lbar();
          // 9) row l2 norms
          {
            const int row = tid >> 5, li = tid & 31;
            float ss = 0.f;
            #pragma unroll
            for (int i = 0; i < 4; ++i) {
              const float4 v = *(const float4*)&mrows[row][(li + i * 32) * 4];
              ss += v.x*v.x + v.y*v.y + v.z*v.z + v.w*v.w;
            }
            ss += __shfl_xor(ss, 16); ss += __shfl_xor(ss, 8);
            ss += __shfl_xor(ss, 4);  ss += __shfl_xor(ss, 2);
            ss += __shfl_xor(ss, 1);
            if (li == 0) invn_s[row] = 1.0f / fmaxf(sqrtf(ss), 1e-12f);
          }
          lbar();
          // 10) sim for t+1 -> atomicAdd den[t+1]
          sim_phase(kn + (size_t)(t + 1) * Bc * Dc,
                    den + (size_t)(t + 1) * Bc,
                    mrows, ew_own, invn_s, tid);
        }
      }
    } else {
      // Reducer: out for t0 = t-2 from bf16x4 packed rp (3-deep pipeline).
      if (t >= 2) {
        const int t0 = t - 2;
        const int rb = bid - NW;
        const int b = rb >> 2;
        const int d0 = (rb & 3) * 128;
        const float dvb = ld1cg(&den[(size_t)t0 * Bc + b]);
        const unsigned long long* rpc = rp16 + (size_t)(t0 & 1) * RP16PAR;
        const int pg = tid >> 5;           // 0..15: group of 8 partials
        const int cu = tid & 31;           // u64 within the 128-col slice
        const size_t cofs = (size_t)(d0 >> 2) + cu;
        float acc[4] = {};
        #pragma unroll
        for (int i = 0; i < 8; ++i) {
          const int p = pg * 8 + i;
          const unsigned long long v =
              ld8cg(&rpc[((size_t)p * Bc + b) * (Dc / 4) + cofs]);
          const unsigned u0 = (unsigned)v, u1 = (unsigned)(v >> 32);
          acc[0] += lo16f(u0); acc[1] += hi16f(u0);
          acc[2] += lo16f(u1); acc[3] += hi16f(u1);
        }
        #pragma unroll
        for (int j = 0; j < 4; ++j) redR[pg][cu * 4 + j] = acc[j];
        __syncthreads();
        if (tid < 128) {
          float s = 0.f;
          #pragma unroll
          for (int p = 0; p < 16; ++p) s += redR[p][tid];
          const size_t oofs = ((size_t)b * Tc + t0) * Dc + d0 + tid;
          const float g  = out[oofs];
          const float cv = cs[oofs];
          out[oofs] = g * cv + (1.0f - g) * (s / dvb);
        }
        __syncthreads();
      }
    }
    if (t < Tc + 1) gbar(flags, (unsigned)(t + 2), bid, tid);
  }
}

// ---------------------------------------------------------------------------
extern "C" void kernel_launch(void* const* d_in, const int* in_sizes, int n_in,
                              void* d_out, int out_size, void* d_ws, size_t ws_size,
                              hipStream_t stream)
{
  const float* cs    = (const float*)d_in[0];
  const float* mem   = (const float*)d_in[1];
  const float* Wk    = (const float*)d_in[2];
  const float* bk    = (const float*)d_in[3];
  const float* We    = (const float*)d_in[4];
  const float* be    = (const float*)d_in[5];
  const float* Ww    = (const float*)d_in[6];
  const float* bw    = (const float*)d_in[7];
  const float* Wg    = (const float*)d_in[8];
  const float* bg    = (const float*)d_in[9];
  const float* gamma = (const float*)d_in[10];
  const float* beta  = (const float*)d_in[11];
  float* ws  = (float*)d_ws;
  float* out = (float*)d_out;

  // zero den accumulators + barrier flags (contiguous region)
  hipMemsetAsync(ws + OFF_DEN, 0,
                 ((size_t)Tc * Bc + 256 * 16) * sizeof(float), stream);

  hipLaunchKernelGGL(k_gemm, dim3(4096), dim3(256), 0, stream,
                     cs, Wk, bk, We, be, Ww, bw, Wg, bg, ws, out);
  hipLaunchKernelGGL(k_knorm, dim3(2048), dim3(256), 0, stream, ws + OFF_KN);
  hipLaunchKernelGGL(k_main, dim3(NBLK), dim3(NT), 0, stream,
                     cs, mem, gamma, beta, ws, out);
}